// Round 2
// baseline (235.035 us; speedup 1.0000x reference)
//
#include <hip/hip_runtime.h>
#include <math.h>

#define D_MODEL 1024
#define D_FF    4096
#define RANK    128
#define M_ROWS  8192

typedef _Float16 f16;
typedef _Float16 f16x8 __attribute__((ext_vector_type(8)));
typedef float    f32x4 __attribute__((ext_vector_type(4)));

#define MFMA16(a, b, c) __builtin_amdgcn_mfma_f32_16x16x32_f16((a), (b), (c), 0, 0, 0)

__device__ __forceinline__ f16x8 ld8(const f16* p) { return *(const f16x8*)p; }

__device__ __forceinline__ f16x8 cvt8(float4 a0, float4 a1) {
    f16x8 r = { (f16)a0.x, (f16)a0.y, (f16)a0.z, (f16)a0.w,
                (f16)a1.x, (f16)a1.y, (f16)a1.z, (f16)a1.w };
    return r;
}

// Fast exact-gelu: erf via Abramowitz-Stegun 7.1.26 (|err| <= 1.5e-7 abs),
// ~16 VALU ops vs ~35 for libm erff. h is rounded to f16 downstream
// (rel 5e-4), so 1.5e-7 abs on erf is invisible in the output.
__device__ __forceinline__ float gelu_fast(float v) {
    float u  = v * 0.70710678118654752440f;
    float au = fabsf(u);
    float t  = __builtin_amdgcn_rcpf(__builtin_fmaf(0.3275911f, au, 1.0f));
    float e  = __expf(-au * au);                      // v_exp_f32 path
    float p  = __builtin_fmaf(1.061405429f, t, -1.453152027f);
    p = __builtin_fmaf(p, t, 1.421413741f);
    p = __builtin_fmaf(p, t, -0.284496736f);
    p = __builtin_fmaf(p, t, 0.254829592f);
    float er = __builtin_fmaf(-p * t, e, 1.0f);       // erf(au)
    er = copysignf(er, u);                            // erf(u)
    return 0.5f * v * (1.0f + er);
}

// ---------------------------------------------------------------------------
// Prep (verbatim-proven): convert/transpose/scale weights into ws (f16).
// ---------------------------------------------------------------------------
__global__ __launch_bounds__(256) void k_prep(
    const float* __restrict__ cfcU, const float* __restrict__ cfcS,
    const float* __restrict__ cfcV, const float* __restrict__ pjU,
    const float* __restrict__ pjS,  const float* __restrict__ pjV,
    f16* __restrict__ w1T, f16* __restrict__ v1,
    f16* __restrict__ w2T, f16* __restrict__ v2)
{
    int i = blockIdx.x * 256 + threadIdx.x;
    if (i < 131072) {
        int r = i >> 10, d = i & 1023;
        w1T[i] = (f16)(cfcU[d * RANK + r] * cfcS[r]);
    } else if (i < 655360) {
        int j = i - 131072;
        v1[j] = (f16)cfcV[j];
    } else if (i < 1179648) {
        int j = i - 655360;
        int r = j >> 12, f = j & 4095;
        w2T[j] = (f16)(pjU[f * RANK + r] * pjS[r]);
    } else if (i < 1310720) {
        int j = i - 1179648;
        v2[j] = (f16)pjV[j];
    }
}

// ---------------------------------------------------------------------------
// Stage 1 (kept from R1, improved the total): t1p[h][m][r] = x @ w1T^T.
// ---------------------------------------------------------------------------
__global__ __launch_bounds__(512, 2) void k_t1(
    const float* __restrict__ x, const f16* __restrict__ w1T,
    f16* __restrict__ t1p)
{
    __shared__ __align__(16) f16 w1s[128 * 520];   // 133120 B

    const int tid  = threadIdx.x;
    const int lane = tid & 63;
    const int wv   = tid >> 6;
    const int wm   = wv & 3, wn = wv >> 2;
    const int m0b  = blockIdx.x * 64;
    const int h    = blockIdx.y;
    const int c    = lane & 15, q = lane >> 4;

#define LOADX(dst, kc)                                                          \
    _Pragma("unroll") for (int kb = 0; kb < 4; ++kb) {                          \
        const float* px = &x[(size_t)(m0b + wm * 16 + c) * D_MODEL +            \
                             h * 512 + (kc) * 128 + kb * 32 + q * 8];           \
        dst[kb][0] = *(const float4*)px;                                        \
        dst[kb][1] = *(const float4*)(px + 4); }

#define COMPUTEKC(src, kc)                                                      \
    _Pragma("unroll") for (int kb = 0; kb < 4; ++kb) {                          \
        f16x8 af = cvt8(src[kb][0], src[kb][1]);                                \
        _Pragma("unroll") for (int nt = 0; nt < 4; ++nt) {                      \
            f16x8 bf = *(const f16x8*)                                          \
                &w1s[(wn * 64 + nt * 16 + c) * 520 + (kc) * 128 + kb * 32 + q * 8]; \
            acc[nt] = MFMA16(af, bf, acc[nt]); } }

    float4 xa[4][2], xb[4][2];
    LOADX(xa, 0)

#pragma unroll
    for (int i = 0; i < 16; ++i) {
        int id = i * 512 + tid;
        int rr = id >> 6, k8 = id & 63;
        *(f16x8*)&w1s[rr * 520 + k8 * 8] =
            ld8(w1T + (size_t)rr * D_MODEL + h * 512 + k8 * 8);
    }
    __syncthreads();

    f32x4 acc[4] = {};
    LOADX(xb, 1)
    COMPUTEKC(xa, 0)
    LOADX(xa, 2)
    COMPUTEKC(xb, 1)
    LOADX(xb, 3)
    COMPUTEKC(xa, 2)
    COMPUTEKC(xb, 3)

    f16* o = t1p + (size_t)h * (M_ROWS * RANK);
#pragma unroll
    for (int nt = 0; nt < 4; ++nt)
#pragma unroll
        for (int i2 = 0; i2 < 4; ++i2)
            o[(size_t)(m0b + wm * 16 + q * 4 + i2) * RANK + wn * 64 + nt * 16 + c] =
                (f16)acc[nt][i2];
#undef LOADX
#undef COMPUTEKC
}

// ---------------------------------------------------------------------------
// Fused stages 2+3 v3: BARRIER-FREE main loop.
// 512 thr = 8 waves, ALL waves share the block's 32 m-rows; wave wv owns
// f-range [wv*512, wv*512+512) in 8 chunks of 64 f. Weights are L2-resident
// (2 MB) -> B-fragments read DIRECT from global (dense 16-line b128 pattern),
// no LDS staging, no __syncthreads in the loop. h round-trips through a
// per-wave 4 KB XOR-swizzled LDS scratch (wave-local lgkmcnt only).
// Each B-frag feeds 2 MFMA (2 m-subtiles). Epilogue: 8-way LDS tree-reduce
// of c3 partials (f32), single f16 t2 output (coalesced f16x8 stores).
// Grid 256 blocks = 1/CU; ~2 waves/SIMD, free-running.
// ---------------------------------------------------------------------------
__global__ __launch_bounds__(512, 2) void k_fused(
    const f16* __restrict__ t1p, const f16* __restrict__ v1,
    const float* __restrict__ bfc, const f16* __restrict__ w2T,
    f16* __restrict__ t2)
{
    __shared__ __align__(16) char smem[67584];     // hs 32KB | reduce 66KB overlay

    const int tid  = threadIdx.x;
    const int lane = tid & 63;
    const int wv   = tid >> 6;                     // 0..7 = f-slice owner
    const int c    = lane & 15, q = lane >> 4;
    const int m0b  = blockIdx.x * 32;
    const int f00  = wv * 512;

    char* hsb = &smem[wv * 4096];                  // per-wave h scratch [32][128B]

    // A2 fragments (rows m0b..m0b+31): sum of the two f16 t1 partials
    f16x8 a2[2][4];
#pragma unroll
    for (int wm2 = 0; wm2 < 2; ++wm2)
#pragma unroll
        for (int kb = 0; kb < 4; ++kb) {
            const size_t off = (size_t)(m0b + wm2 * 16 + c) * RANK + kb * 32 + q * 8;
            f16x8 p0 = ld8(t1p + off);
            f16x8 p1 = ld8(t1p + (size_t)(M_ROWS * RANK) + off);
#pragma unroll
            for (int e = 0; e < 8; ++e)
                a2[wm2][kb][e] = (f16)((float)p0[e] + (float)p1[e]);
        }

    f32x4 c3[2][8] = {};

#define LOADBV(BV, ch)                                                          \
    { const int ff = f00 + (ch) * 64;                                           \
      _Pragma("unroll") for (int nt = 0; nt < 4; ++nt)                          \
      _Pragma("unroll") for (int kb = 0; kb < 4; ++kb)                          \
          BV[nt][kb] = ld8(v1 + (size_t)(ff + nt * 16 + c) * RANK + kb * 32 + q * 8); }

#define CHUNK(BV, BN, ch, PF)                                                   \
    { const int f0 = f00 + (ch) * 64;                                           \
      /* stage 2: h-tile = t1 @ v1^T, each BV frag feeds 2 MFMA */              \
      f32x4 c2[2][4] = {};                                                      \
      _Pragma("unroll") for (int nt = 0; nt < 4; ++nt)                          \
      _Pragma("unroll") for (int kb = 0; kb < 4; ++kb) {                        \
          c2[0][nt] = MFMA16(a2[0][kb], BV[nt][kb], c2[0][nt]);                 \
          c2[1][nt] = MFMA16(a2[1][kb], BV[nt][kb], c2[1][nt]);                 \
      }                                                                         \
      if (PF) LOADBV(BN, (ch) + 1)         /* next-chunk loads fly under gelu */\
      float bb[4];                                                              \
      _Pragma("unroll") for (int nt = 0; nt < 4; ++nt)                          \
          bb[nt] = bfc[f0 + nt * 16 + c];                                       \
      /* bias + gelu -> per-wave hs, XOR-swizzled rows of 128 B */              \
      _Pragma("unroll") for (int wm2 = 0; wm2 < 2; ++wm2)                       \
      _Pragma("unroll") for (int nt = 0; nt < 4; ++nt)                          \
      _Pragma("unroll") for (int i2 = 0; i2 < 4; ++i2) {                        \
          int row = wm2 * 16 + q * 4 + i2;                                      \
          int col = ((nt * 16 + c) * 2) ^ ((row & 7) << 4);                     \
          *(f16*)(hsb + row * 128 + col) =                                      \
              (f16)gelu_fast(c2[wm2][nt][i2] + bb[nt]);                         \
      }                                                                         \
      asm volatile("s_waitcnt lgkmcnt(0)" ::: "memory"); /* cross-lane RAW */   \
      /* stage 3: c3 += h @ w2T^T, B direct from global */                      \
      _Pragma("unroll") for (int kb2 = 0; kb2 < 2; ++kb2) {                     \
          f16x8 bw[8];                                                          \
          _Pragma("unroll") for (int rt = 0; rt < 8; ++rt)                      \
              bw[rt] = ld8(w2T + (size_t)(rt * 16 + c) * D_FF +                 \
                           f0 + kb2 * 32 + q * 8);                              \
          f16x8 a3[2];                                                          \
          _Pragma("unroll") for (int wm2 = 0; wm2 < 2; ++wm2) {                 \
              int row = wm2 * 16 + c;                                           \
              int col = (kb2 * 64 + q * 16) ^ ((row & 7) << 4);                 \
              a3[wm2] = *(const f16x8*)(hsb + row * 128 + col);                 \
          }                                                                     \
          _Pragma("unroll") for (int rt = 0; rt < 8; ++rt) {                    \
              c3[0][rt] = MFMA16(a3[0], bw[rt], c3[0][rt]);                     \
              c3[1][rt] = MFMA16(a3[1], bw[rt], c3[1][rt]);                     \
          }                                                                     \
      }                                                                         \
      asm volatile("s_waitcnt lgkmcnt(0)" ::: "memory"); /* WAR on hs */        \
    }

    f16x8 bva[4][4], bvb[4][4];
    LOADBV(bva, 0)
#pragma unroll 1
    for (int ch = 0; ch < 8; ch += 2) {
        CHUNK(bva, bvb, ch, true)
        CHUNK(bvb, bva, ch + 1, ch + 2 < 8)
    }
#undef LOADBV
#undef CHUNK

    // ---- epilogue: 8-way tree reduce of c3 over wv, then coalesced f16 write
    float* rbuf = (float*)smem;                    // 4 regions of [32][132] f32

#define ST_C3(w)                                                                \
    { float* rb = rbuf + (w) * 4224;                                            \
      _Pragma("unroll") for (int wm2 = 0; wm2 < 2; ++wm2)                       \
      _Pragma("unroll") for (int rt = 0; rt < 8; ++rt)                          \
      _Pragma("unroll") for (int i2 = 0; i2 < 4; ++i2)                          \
          rb[(wm2 * 16 + q * 4 + i2) * 132 + rt * 16 + c] = c3[wm2][rt][i2]; }
#define ADD_C3(w)                                                               \
    { float* rb = rbuf + (w) * 4224;                                            \
      _Pragma("unroll") for (int wm2 = 0; wm2 < 2; ++wm2)                       \
      _Pragma("unroll") for (int rt = 0; rt < 8; ++rt)                          \
      _Pragma("unroll") for (int i2 = 0; i2 < 4; ++i2)                          \
          c3[wm2][rt][i2] += rb[(wm2 * 16 + q * 4 + i2) * 132 + rt * 16 + c]; }

    __syncthreads();                               // hs dead; overlay reduce
    if (wv >= 4) ST_C3(wv - 4)
    __syncthreads();
    if (wv < 4) ADD_C3(wv)
    __syncthreads();
    if (wv == 2 || wv == 3) ST_C3(wv - 2)
    __syncthreads();
    if (wv < 2) ADD_C3(wv)
    __syncthreads();
    if (wv == 1) ST_C3(0)
    __syncthreads();
    if (wv == 0) { ADD_C3(0) ST_C3(1) }            // park final f32 in region 1
    __syncthreads();
#undef ST_C3
#undef ADD_C3

    {   // all 512 threads: region1 [32][132] f32 -> t2 [32][128] f16 coalesced
        const int mrow = tid >> 4;                 // 0..31
        const int r8   = (tid & 15) * 8;
        const float* rb = rbuf + 4224 + mrow * 132 + r8;
        float4 lo = *(const float4*)rb;
        float4 hi = *(const float4*)(rb + 4);
        *(f16x8*)&t2[(size_t)(m0b + mrow) * RANK + r8] = cvt8(lo, hi);
    }
}

// ---------------------------------------------------------------------------
// Stage 4: out = t2 @ v2^T + bpj (t2 now a single f16 tensor, no partial add).
// ---------------------------------------------------------------------------
__global__ __launch_bounds__(256, 2) void k_out(
    const f16* __restrict__ t2, const f16* __restrict__ v2,
    const float* __restrict__ bpj, float* __restrict__ out)
{
    __shared__ __align__(16) f16 v2s[256 * 136];

    const int tid  = threadIdx.x;
    const int lane = tid & 63;
    const int wv   = tid >> 6;
    const int wm   = wv & 1, wn = wv >> 1;
    const int m0b  = blockIdx.x * 32;
    const int n0b  = blockIdx.y * 256;
    const int c    = lane & 15, q = lane >> 4;

#pragma unroll
    for (int i8 = 0; i8 < 16; ++i8) {
        int id = i8 * 256 + tid;
        int nn = id >> 4, k8 = id & 15;
        *(f16x8*)&v2s[nn * 136 + k8 * 8] =
            ld8(v2 + (size_t)(n0b + nn) * RANK + k8 * 8);
    }

    f16x8 a[4];
#pragma unroll
    for (int kb = 0; kb < 4; ++kb)
        a[kb] = ld8(t2 + (size_t)(m0b + wm * 16 + c) * RANK + kb * 32 + q * 8);
    __syncthreads();

    f32x4 acc[8] = {};
#pragma unroll
    for (int nt = 0; nt < 8; ++nt)
#pragma unroll
        for (int kb = 0; kb < 4; ++kb) {
            f16x8 bf = *(const f16x8*)
                &v2s[(wn * 128 + nt * 16 + c) * 136 + kb * 32 + q * 8];
            acc[nt] = MFMA16(a[kb], bf, acc[nt]);
        }

#pragma unroll
    for (int nt = 0; nt < 8; ++nt) {
        float b = bpj[n0b + wn * 128 + nt * 16 + c];
#pragma unroll
        for (int i2 = 0; i2 < 4; ++i2)
            out[(size_t)(m0b + wm * 16 + q * 4 + i2) * D_MODEL +
                n0b + wn * 128 + nt * 16 + c] = acc[nt][i2] + b;
    }
}

extern "C" void kernel_launch(void* const* d_in, const int* in_sizes, int n_in,
                              void* d_out, int out_size, void* d_ws, size_t ws_size,
                              hipStream_t stream) {
    const float* x    = (const float*)d_in[0];
    const float* cfcU = (const float*)d_in[1];
    const float* cfcS = (const float*)d_in[2];
    const float* cfcV = (const float*)d_in[3];
    const float* cfcB = (const float*)d_in[4];
    const float* pjU  = (const float*)d_in[5];
    const float* pjS  = (const float*)d_in[6];
    const float* pjV  = (const float*)d_in[7];
    const float* pjB  = (const float*)d_in[8];
    float* out = (float*)d_out;

    // ws layout (f16 elements), <= 10.5 MB (12 MB proven safe):
    f16* wsf = (f16*)d_ws;
    f16* t1p = wsf;                 // [2][8192*128]  4 MB
    f16* t2  = wsf + 2097152;       // [8192*128]     2 MB (single, was 2 partials)
    f16* w1T = wsf + 4194304;       // [128*1024]
    f16* v1  = w1T + 131072;        // [4096*128]
    f16* w2T = v1  + 524288;        // [128*4096]
    f16* v2  = w2T + 524288;        // [1024*128]

    k_prep <<<dim3(5120), 256, 0, stream>>>(cfcU, cfcS, cfcV, pjU, pjS, pjV,
                                            w1T, v1, w2T, v2);
    k_t1   <<<dim3(M_ROWS / 64, 2), 512, 0, stream>>>(x, w1T, t1p);
    k_fused<<<dim3(M_ROWS / 32), 512, 0, stream>>>(t1p, v1, cfcB, w2T, t2);
    k_out  <<<dim3(M_ROWS / 32, D_MODEL / 256), 256, 0, stream>>>(t2, v2, pjB, out);
}

// Round 4
// 194.327 us; speedup vs baseline: 1.2095x; 1.2095x over previous
//
#include <hip/hip_runtime.h>
#include <math.h>

#define D_MODEL 1024
#define D_FF    4096
#define RANK    128
#define M_ROWS  8192

typedef _Float16 f16;
typedef _Float16 f16x8 __attribute__((ext_vector_type(8)));
typedef float    f32x4 __attribute__((ext_vector_type(4)));

#define MFMA16(a, b, c) __builtin_amdgcn_mfma_f32_16x16x32_f16((a), (b), (c), 0, 0, 0)

__device__ __forceinline__ f16x8 ld8(const f16* p) { return *(const f16x8*)p; }

__device__ __forceinline__ f16x8 cvt8(float4 a0, float4 a1) {
    f16x8 r = { (f16)a0.x, (f16)a0.y, (f16)a0.z, (f16)a0.w,
                (f16)a1.x, (f16)a1.y, (f16)a1.z, (f16)a1.w };
    return r;
}

// Fast exact-gelu: erf via Abramowitz-Stegun 7.1.26 (|err| <= 1.5e-7 abs),
// proven R2 (absmax unchanged at 9.77e-4).
__device__ __forceinline__ float gelu_fast(float v) {
    float u  = v * 0.70710678118654752440f;
    float au = fabsf(u);
    float t  = __builtin_amdgcn_rcpf(__builtin_fmaf(0.3275911f, au, 1.0f));
    float e  = __expf(-au * au);
    float p  = __builtin_fmaf(1.061405429f, t, -1.453152027f);
    p = __builtin_fmaf(p, t, 1.421413741f);
    p = __builtin_fmaf(p, t, -0.284496736f);
    p = __builtin_fmaf(p, t, 0.254829592f);
    float er = __builtin_fmaf(-p * t, e, 1.0f);
    er = copysignf(er, u);
    return 0.5f * v * (1.0f + er);
}

// ---------------------------------------------------------------------------
// Prep (verbatim-proven).
// ---------------------------------------------------------------------------
__global__ __launch_bounds__(256) void k_prep(
    const float* __restrict__ cfcU, const float* __restrict__ cfcS,
    const float* __restrict__ cfcV, const float* __restrict__ pjU,
    const float* __restrict__ pjS,  const float* __restrict__ pjV,
    f16* __restrict__ w1T, f16* __restrict__ v1,
    f16* __restrict__ w2T, f16* __restrict__ v2)
{
    int i = blockIdx.x * 256 + threadIdx.x;
    if (i < 131072) {
        int r = i >> 10, d = i & 1023;
        w1T[i] = (f16)(cfcU[d * RANK + r] * cfcS[r]);
    } else if (i < 655360) {
        int j = i - 131072;
        v1[j] = (f16)cfcV[j];
    } else if (i < 1179648) {
        int j = i - 655360;
        int r = j >> 12, f = j & 4095;
        w2T[j] = (f16)(pjU[f * RANK + r] * pjS[r]);
    } else if (i < 1310720) {
        int j = i - 1179648;
        v2[j] = (f16)pjV[j];
    }
}

// ---------------------------------------------------------------------------
// Stage 1 (proven R1): t1p[h][m][r] = x[m][K-half h] @ w1T^T.
// ---------------------------------------------------------------------------
__global__ __launch_bounds__(512, 2) void k_t1(
    const float* __restrict__ x, const f16* __restrict__ w1T,
    f16* __restrict__ t1p)
{
    __shared__ __align__(16) f16 w1s[128 * 520];   // 133120 B

    const int tid  = threadIdx.x;
    const int lane = tid & 63;
    const int wv   = tid >> 6;
    const int wm   = wv & 3, wn = wv >> 2;
    const int m0b  = blockIdx.x * 64;
    const int h    = blockIdx.y;
    const int c    = lane & 15, q = lane >> 4;

#define LOADX(dst, kc)                                                          \
    _Pragma("unroll") for (int kb = 0; kb < 4; ++kb) {                          \
        const float* px = &x[(size_t)(m0b + wm * 16 + c) * D_MODEL +            \
                             h * 512 + (kc) * 128 + kb * 32 + q * 8];           \
        dst[kb][0] = *(const float4*)px;                                        \
        dst[kb][1] = *(const float4*)(px + 4); }

#define COMPUTEKC(src, kc)                                                      \
    _Pragma("unroll") for (int kb = 0; kb < 4; ++kb) {                          \
        f16x8 af = cvt8(src[kb][0], src[kb][1]);                                \
        _Pragma("unroll") for (int nt = 0; nt < 4; ++nt) {                      \
            f16x8 bf = *(const f16x8*)                                          \
                &w1s[(wn * 64 + nt * 16 + c) * 520 + (kc) * 128 + kb * 32 + q * 8]; \
            acc[nt] = MFMA16(af, bf, acc[nt]); } }

    float4 xa[4][2], xb[4][2];
    LOADX(xa, 0)

#pragma unroll
    for (int i = 0; i < 16; ++i) {
        int id = i * 512 + tid;
        int rr = id >> 6, k8 = id & 63;
        *(f16x8*)&w1s[rr * 520 + k8 * 8] =
            ld8(w1T + (size_t)rr * D_MODEL + h * 512 + k8 * 8);
    }
    __syncthreads();

    f32x4 acc[4] = {};
    LOADX(xb, 1)
    COMPUTEKC(xa, 0)
    LOADX(xa, 2)
    COMPUTEKC(xb, 1)
    LOADX(xb, 3)
    COMPUTEKC(xa, 2)
    COMPUTEKC(xb, 3)

    f16* o = t1p + (size_t)h * (M_ROWS * RANK);
#pragma unroll
    for (int nt = 0; nt < 4; ++nt)
#pragma unroll
        for (int i2 = 0; i2 < 4; ++i2)
            o[(size_t)(m0b + wm * 16 + q * 4 + i2) * RANK + wn * 64 + nt * 16 + c] =
                (f16)acc[nt][i2];
#undef LOADX
#undef COMPUTEKC
}

// ---------------------------------------------------------------------------
// Fused stages 2+3 v4: barrier-free loop, REGISTER-BUDGETED (R2 post-mortem:
// v3 spilled 250 MB/dispatch under the 128-VGPR cap of 512thr x 2blk).
// 256 thr = 4 waves, all sharing 32 m-rows; wave wv owns f-slice
// [s*2048 + wv*512, +512) in 8 chunks of 64 f. B-frags direct from global
// (L2-resident: XCD swizzle keeps each XCD on one f-half = 1 MB weights).
// No B double-buffer: bv (64 VGPR) dies at stage2; bw (64 VGPR) issued
// before gelu so its ~1300-cy VALU hides the L2 latency. Peak live ~210
// VGPR < 256 budget (launch_bounds(256,2)). h via per-wave 4 KB XOR-swizzled
// LDS scratch (wave-local lgkmcnt only, proven v3). Epilogue: 4-wave tree
// reduce, f16 partial t2p[s]. Grid 512 = 2 blocks/CU, full chip.
// ---------------------------------------------------------------------------
__global__ __launch_bounds__(256, 2) void k_fused(
    const f16* __restrict__ t1p, const f16* __restrict__ v1,
    const float* __restrict__ bfc, const f16* __restrict__ w2T,
    f16* __restrict__ t2p)
{
    __shared__ __align__(16) char smem[33792];     // hs 16KB | reduce overlay

    const int tid  = threadIdx.x;
    const int lane = tid & 63;
    const int wv   = tid >> 6;                     // 0..3
    const int c    = lane & 15, q = lane >> 4;

    // XCD swizzle (bijective, 512 = 64*8): XCDs 0-3 -> s=0, 4-7 -> s=1
    const int bx  = blockIdx.x;
    const int s   = (bx & 7) >> 2;
    const int mb  = (bx >> 3) * 4 + (bx & 3);      // 0..255
    const int m0b = mb * 32;
    const int f00 = s * 2048 + wv * 512;

    char* hsb = &smem[wv * 4096];                  // per-wave h scratch [32][128B]

    // A2 fragments: f16 sum of the two t1 partials (proven)
    f16x8 a2[2][4];
#pragma unroll
    for (int wm2 = 0; wm2 < 2; ++wm2)
#pragma unroll
        for (int kb = 0; kb < 4; ++kb) {
            const size_t off = (size_t)(m0b + wm2 * 16 + c) * RANK + kb * 32 + q * 8;
            f16x8 p0 = ld8(t1p + off);
            f16x8 p1 = ld8(t1p + (size_t)(M_ROWS * RANK) + off);
#pragma unroll
            for (int e = 0; e < 8; ++e)
                a2[wm2][kb][e] = (f16)((float)p0[e] + (float)p1[e]);
        }

    f32x4 c3[2][8] = {};

#pragma unroll 1
    for (int ch = 0; ch < 8; ++ch) {
        const int f0 = f00 + ch * 64;

        // ---- load stage-2 B frags (bv dies at end of stage 2)
        f16x8 bv[4][4];
#pragma unroll
        for (int nt = 0; nt < 4; ++nt)
#pragma unroll
            for (int kb = 0; kb < 4; ++kb)
                bv[nt][kb] = ld8(v1 + (size_t)(f0 + nt * 16 + c) * RANK + kb * 32 + q * 8);
        // bias loads fly under stage 2
        float bb[4];
#pragma unroll
        for (int nt = 0; nt < 4; ++nt)
            bb[nt] = bfc[f0 + nt * 16 + c];

        // ---- stage 2: h-tile = t1 @ v1^T (each bv frag feeds 2 MFMA)
        f32x4 c2[2][4] = {};
#pragma unroll
        for (int nt = 0; nt < 4; ++nt)
#pragma unroll
            for (int kb = 0; kb < 4; ++kb) {
                c2[0][nt] = MFMA16(a2[0][kb], bv[nt][kb], c2[0][nt]);
                c2[1][nt] = MFMA16(a2[1][kb], bv[nt][kb], c2[1][nt]);
            }

        // ---- issue stage-3 B frags now; gelu's VALU hides their latency
        f16x8 bw[2][8];
#pragma unroll
        for (int kb2 = 0; kb2 < 2; ++kb2)
#pragma unroll
            for (int rt = 0; rt < 8; ++rt)
                bw[kb2][rt] = ld8(w2T + (size_t)(rt * 16 + c) * D_FF +
                                  f0 + kb2 * 32 + q * 8);

        // ---- bias + gelu -> per-wave hs, XOR-swizzled rows of 128 B
#pragma unroll
        for (int wm2 = 0; wm2 < 2; ++wm2)
#pragma unroll
            for (int nt = 0; nt < 4; ++nt)
#pragma unroll
                for (int i2 = 0; i2 < 4; ++i2) {
                    int row = wm2 * 16 + q * 4 + i2;
                    int col = ((nt * 16 + c) * 2) ^ ((row & 7) << 4);
                    *(f16*)(hsb + row * 128 + col) =
                        (f16)gelu_fast(c2[wm2][nt][i2] + bb[nt]);
                }
        asm volatile("s_waitcnt lgkmcnt(0)" ::: "memory"); // cross-lane RAW

        // ---- stage 3: c3 += h @ w2T^T
#pragma unroll
        for (int kb2 = 0; kb2 < 2; ++kb2) {
            f16x8 a3[2];
#pragma unroll
            for (int wm2 = 0; wm2 < 2; ++wm2) {
                int row = wm2 * 16 + c;
                int col = (kb2 * 64 + q * 16) ^ ((row & 7) << 4);
                a3[wm2] = *(const f16x8*)(hsb + row * 128 + col);
            }
#pragma unroll
            for (int rt = 0; rt < 8; ++rt) {
                c3[0][rt] = MFMA16(a3[0], bw[kb2][rt], c3[0][rt]);
                c3[1][rt] = MFMA16(a3[1], bw[kb2][rt], c3[1][rt]);
            }
        }
        asm volatile("s_waitcnt lgkmcnt(0)" ::: "memory"); // WAR on hs
    }

    // ---- epilogue: 4-way tree reduce of c3 over wv, write f16 partial t2p[s]
    float* rbuf = (float*)smem;                    // 2 regions of [32][132] f32

#define ST_C3(w)                                                                \
    { float* rb = rbuf + (w) * 4224;                                            \
      _Pragma("unroll") for (int wm2 = 0; wm2 < 2; ++wm2)                       \
      _Pragma("unroll") for (int rt = 0; rt < 8; ++rt)                          \
      _Pragma("unroll") for (int i2 = 0; i2 < 4; ++i2)                          \
          rb[(wm2 * 16 + q * 4 + i2) * 132 + rt * 16 + c] = c3[wm2][rt][i2]; }
#define ADD_C3(w)                                                               \
    { float* rb = rbuf + (w) * 4224;                                            \
      _Pragma("unroll") for (int wm2 = 0; wm2 < 2; ++wm2)                       \
      _Pragma("unroll") for (int rt = 0; rt < 8; ++rt)                          \
      _Pragma("unroll") for (int i2 = 0; i2 < 4; ++i2)                          \
          c3[wm2][rt][i2] += rb[(wm2 * 16 + q * 4 + i2) * 132 + rt * 16 + c]; }

    __syncthreads();                               // all waves done with hs
    if (wv >= 2) ST_C3(wv - 2)
    __syncthreads();
    if (wv < 2) ADD_C3(wv)
    __syncthreads();
    if (wv == 1) ST_C3(0)
    __syncthreads();
    if (wv == 0) {
        ADD_C3(0)
        f16* o = t2p + (size_t)s * (M_ROWS * RANK);
#pragma unroll
        for (int wm2 = 0; wm2 < 2; ++wm2)
#pragma unroll
            for (int rt = 0; rt < 8; ++rt)
#pragma unroll
                for (int i2 = 0; i2 < 4; ++i2)
                    o[(size_t)(m0b + wm2 * 16 + q * 4 + i2) * RANK + rt * 16 + c] =
                        (f16)c3[wm2][rt][i2];
    }
#undef ST_C3
#undef ADD_C3
}

// ---------------------------------------------------------------------------
// Stage 4 (proven R0/R1): out = (t2p0+t2p1) @ v2^T + bpj, fp32 out.
// ---------------------------------------------------------------------------
__global__ __launch_bounds__(256, 2) void k_out(
    const f16* __restrict__ t2p, const f16* __restrict__ v2,
    const float* __restrict__ bpj, float* __restrict__ out)
{
    __shared__ __align__(16) f16 v2s[256 * 136];

    const int tid  = threadIdx.x;
    const int lane = tid & 63;
    const int wv   = tid >> 6;
    const int wm   = wv & 1, wn = wv >> 1;
    const int m0b  = blockIdx.x * 32;
    const int n0b  = blockIdx.y * 256;
    const int c    = lane & 15, q = lane >> 4;

#pragma unroll
    for (int i8 = 0; i8 < 16; ++i8) {
        int id = i8 * 256 + tid;
        int nn = id >> 4, k8 = id & 15;
        *(f16x8*)&v2s[nn * 136 + k8 * 8] =
            ld8(v2 + (size_t)(n0b + nn) * RANK + k8 * 8);
    }

    f16x8 a[4];
#pragma unroll
    for (int kb = 0; kb < 4; ++kb) {
        const size_t off = (size_t)(m0b + wm * 16 + c) * RANK + kb * 32 + q * 8;
        f16x8 p0 = ld8(t2p + off);
        f16x8 p1 = ld8(t2p + (size_t)(M_ROWS * RANK) + off);
#pragma unroll
        for (int e = 0; e < 8; ++e)
            a[kb][e] = (f16)((float)p0[e] + (float)p1[e]);
    }
    __syncthreads();

    f32x4 acc[8] = {};
#pragma unroll
    for (int nt = 0; nt < 8; ++nt)
#pragma unroll
        for (int kb = 0; kb < 4; ++kb) {
            f16x8 bf = *(const f16x8*)
                &v2s[(wn * 128 + nt * 16 + c) * 136 + kb * 32 + q * 8];
            acc[nt] = MFMA16(a[kb], bf, acc[nt]);
        }

#pragma unroll
    for (int nt = 0; nt < 8; ++nt) {
        float b = bpj[n0b + wn * 128 + nt * 16 + c];
#pragma unroll
        for (int i2 = 0; i2 < 4; ++i2)
            out[(size_t)(m0b + wm * 16 + q * 4 + i2) * D_MODEL +
                n0b + wn * 128 + nt * 16 + c] = acc[nt][i2] + b;
    }
}

extern "C" void kernel_launch(void* const* d_in, const int* in_sizes, int n_in,
                              void* d_out, int out_size, void* d_ws, size_t ws_size,
                              hipStream_t stream) {
    const float* x    = (const float*)d_in[0];
    const float* cfcU = (const float*)d_in[1];
    const float* cfcS = (const float*)d_in[2];
    const float* cfcV = (const float*)d_in[3];
    const float* cfcB = (const float*)d_in[4];
    const float* pjU  = (const float*)d_in[5];
    const float* pjS  = (const float*)d_in[6];
    const float* pjV  = (const float*)d_in[7];
    const float* pjB  = (const float*)d_in[8];
    float* out = (float*)d_out;

    // ws layout (f16 elements), 10.5 MB (12 MB proven safe):
    f16* wsf = (f16*)d_ws;
    f16* t1p = wsf;                 // [2][8192*128]  4 MB
    f16* t2p = wsf + 2097152;       // [2][8192*128]  4 MB
    f16* w1T = wsf + 4194304;       // [128*1024]
    f16* v1  = w1T + 131072;        // [4096*128]
    f16* w2T = v1  + 524288;        // [128*4096]
    f16* v2  = w2T + 524288;        // [1024*128]

    k_prep <<<dim3(5120), 256, 0, stream>>>(cfcU, cfcS, cfcV, pjU, pjS, pjV,
                                            w1T, v1, w2T, v2);
    k_t1   <<<dim3(M_ROWS / 64, 2), 512, 0, stream>>>(x, w1T, t1p);
    k_fused<<<dim3(512), 256, 0, stream>>>(t1p, v1, cfcB, w2T, t2p);
    k_out  <<<dim3(M_ROWS / 32, D_MODEL / 256), 256, 0, stream>>>(t2p, v2, pjB, out);
}